// Round 13
// baseline (114.851 us; speedup 1.0000x reference)
//
#include <hip/hip_runtime.h>
#include <hip/hip_bf16.h>
#include <stdint.h>

#define BDIM 32
#define SDIM 4096
#define SP1  4097
#define EDIM 256
#define FDIM 256
#define LDIM 50
#define TTILE 128
#define NT    32   // 32 tiles x 128 = 4096; position 4096 handled in final_kernel

typedef __attribute__((ext_vector_type(8)))  short bf16x8v;
typedef __attribute__((ext_vector_type(16))) float f32x16;

__device__ __forceinline__ unsigned short f2bf(float f) {
    union { float f; uint32_t u; } v; v.f = f;
    uint32_t u = v.u;
    uint32_t r = (u + 0x7fffu + ((u >> 16) & 1u)) >> 16;
    return (unsigned short)r;
}

// tanh(x) = 1 - 2/(1+e^{2x}); v_rcp_f32 (~1ulp) is plenty vs bf16 storage noise.
__device__ __forceinline__ float tanh_fast(float x) {
    float e = __expf(2.0f * x);
    float r = __builtin_amdgcn_rcpf(e + 1.0f);
    return fmaf(-2.0f, r, 1.0f);
}

// Scalar casts -> compiler emits v_cvt_pk_bf16_f32 (m240: don't hand-write).
__device__ __forceinline__ uint32_t pack_bf2(float lo, float hi) {
    union { __hip_bfloat162 v; uint32_t u; } cv;
    cv.v = __halves2bfloat162(__float2bfloat16(lo), __float2bfloat16(hi));
    return cv.u;
}

__device__ __forceinline__ void load_lds16(const void* g, uint32_t* l) {
    __builtin_amdgcn_global_load_lds(
        (const __attribute__((address_space(1))) uint32_t*)g,
        (__attribute__((address_space(3))) uint32_t*)l, 16, 0, 0);
}

// ---- Prep: embb (fp32->bf16), Wb3[g16][half][f][8], W2k3[kc][half][cg][8], Wt01, zp ----
__global__ void prep_all(const float* __restrict__ emb, const float* __restrict__ conv_w,
                         const float* __restrict__ U_w, const float* __restrict__ final_w,
                         unsigned short* __restrict__ embb, unsigned short* __restrict__ Wb3,
                         unsigned short* __restrict__ W2k3, float* __restrict__ Wt01,
                         uint32_t* __restrict__ zp)
{
    int o = blockIdx.x * 256 + threadIdx.x;          // grid 3816 -> o < 976896
    size_t eo = (size_t)o * 8;
    if (eo < (size_t)30522 * 256) {
        float4 v0 = *(const float4*)(emb + eo);
        float4 v1 = *(const float4*)(emb + eo + 4);
        union { unsigned short u[8]; uint4 q; } pk;
        pk.u[0] = f2bf(v0.x); pk.u[1] = f2bf(v0.y); pk.u[2] = f2bf(v0.z); pk.u[3] = f2bf(v0.w);
        pk.u[4] = f2bf(v1.x); pk.u[5] = f2bf(v1.y); pk.u[6] = f2bf(v1.z); pk.u[7] = f2bf(v1.w);
        *(uint4*)(embb + eo) = pk.q;
    }
    if (o < 262144) {                                // Wb3: offset = g16*4096 + half*2048 + f*8 + j
        int j = o & 7, f = (o >> 3) & 255, half = (o >> 11) & 1, g16 = o >> 12;
        int kg = g16 * 16 + half * 8 + j;            // global K index = tap*256 + e
        int e = kg & 255, tap = kg >> 8;
        Wb3[o] = f2bf(conv_w[f * 1024 + e * 4 + tap]);
    }
    if (o < 32768) {                                 // W2k3: offset = kc*2048 + half*1024 + cg*8 + j
        int j = o & 7, cg = (o >> 3) & 127, half = (o >> 10) & 1, kc = o >> 11;
        int k = kc * 16 + half * 8 + j;
        float v = 0.f;
        if (cg < 64) { if (cg < LDIM) v = U_w[cg * FDIM + k]; }
        else         { int cl = cg - 64; if (cl < LDIM) v = final_w[cl * FDIM + k]; }
        W2k3[o] = f2bf(v);
    }
    if (o < 65536) {
        int f = o & 255, e = o >> 8;                 // Wt01[e][f] = taps 0,1 (fp32 exact)
        Wt01[(size_t)o * 2]     = conv_w[f * 1024 + e * 4];
        Wt01[(size_t)o * 2 + 1] = conv_w[f * 1024 + e * 4 + 1];
    }
    if (o < 128) zp[o] = 0;
}

// ---- Fused: gather -> conv1d+tanh (LDS H-tile) -> scores|t GEMM -> softmax partials ----
// 32x32x16 MFMA. Conv: wave = 64f x 128t (2x4 frags), K-steps of 16 (tap-major).
// P: wave = 64 rows x (32 score + 32 t cols); label's score & t share a lane.
__global__ __launch_bounds__(256, 2) void fused_kernel(
    const int* __restrict__ ids, const unsigned short* __restrict__ embb,
    const unsigned short* __restrict__ Wb3, const float* __restrict__ conv_b,
    const unsigned short* __restrict__ W2k3, const uint32_t* __restrict__ zp,
    float* __restrict__ part)
{
    __shared__ uint32_t xs[132 * 128];   // 67,584 B: x rows 0..130, reused as H-tile

    const int tid  = threadIdx.x;
    const int lane = tid & 63;
    const int wid  = tid >> 6;
    const int b    = blockIdx.y;
    const int tile = blockIdx.x;
    const int t0   = tile * TTILE;
    const int l31  = lane & 31;
    const int hi5  = lane >> 5;
    const int q    = lane & 31;
    const int half = lane >> 5;

    // ---- stage rows 0..130 (p = t0-2+r): all ids first, then all gathers ----
    {
        int nid[17];
        #pragma unroll
        for (int j = 0; j < 17; ++j) {
            int r0 = wid * 2 + j * 8;
            int r  = r0 + half;
            int p  = t0 - 2 + r;
            nid[j] = -1;
            if (r0 < 131 && r < 131 && (unsigned)p < SDIM)
                nid[j] = ids[b * SDIM + p];
        }
        const unsigned short* zs = (const unsigned short*)zp + q * 8;
        #pragma unroll
        for (int j = 0; j < 17; ++j) {
            int r0 = wid * 2 + j * 8;
            if (r0 >= 131) continue;                 // wave-uniform guard
            int r = r0 + half;
            const unsigned short* s = (nid[j] >= 0)
                ? embb + (size_t)nid[j] * EDIM + (((uint32_t)(q * 16) ^ ((uint32_t)(r & 7) << 4)) >> 1)
                : zs;
            load_lds16(s, &xs[r0 * 128]);
        }
    }
    __syncthreads();

    // ---- Conv GEMM: wave = 64 filters (M) x 128 positions (N), K=1024, steps of 16 ----
    const int fbase = wid * 64;
    // Wb3 per-lane base: ((g16*2 + hi5)*256 + f)*8 shorts; mf adds 32*8=256 shorts.
    const unsigned short* afbase = Wb3 + ((size_t)hi5 * 256 + fbase + l31) * 8;

    f32x16 acc[2][4];
    #pragma unroll
    for (int a = 0; a < 2; ++a)
        #pragma unroll
        for (int n = 0; n < 4; ++n)
            acc[a][n] = (f32x16){0,0,0,0,0,0,0,0,0,0,0,0,0,0,0,0};

    bf16x8v afc[2];
    afc[0] = *(const bf16x8v*)(afbase);              // g16=0, mf=0
    afc[1] = *(const bf16x8v*)(afbase + 256);        // g16=0, mf=1

    #pragma unroll 1
    for (int tap = 0; tap < 4; ++tap) {
        uint32_t bb[4];
        #pragma unroll
        for (int n = 0; n < 4; ++n) {
            int r = n * 32 + l31 + tap;
            bb[n] = (uint32_t)(r * 512) ^ (uint32_t)(hi5 * 16) ^ (uint32_t)((r & 7) << 4);
        }
        const unsigned short* afg = afbase + (size_t)tap * 65536;   // 16 g16-steps * 4096
        #pragma unroll
        for (int ke = 0; ke < 16; ++ke) {
            // prefetch next g16's A-fragments (always 2 loads in flight)
            const unsigned short* nxt = (ke < 15)
                ? (afg + (size_t)(ke + 1) * 4096)
                : (afbase + (size_t)((tap + 1) & 3) * 65536);
            bf16x8v afn0 = *(const bf16x8v*)(nxt);
            bf16x8v afn1 = *(const bf16x8v*)(nxt + 256);

            bf16x8v bfr[4];
            #pragma unroll
            for (int n = 0; n < 4; ++n)
                bfr[n] = *(const bf16x8v*)((const char*)xs + (bb[n] ^ (uint32_t)(ke * 32)));

            __builtin_amdgcn_s_setprio(1);
            #pragma unroll
            for (int n = 0; n < 4; ++n) {
                acc[0][n] = __builtin_amdgcn_mfma_f32_32x32x16_bf16(afc[0], bfr[n], acc[0][n], 0, 0, 0);
                acc[1][n] = __builtin_amdgcn_mfma_f32_32x32x16_bf16(afc[1], bfr[n], acc[1][n], 0, 0, 0);
            }
            __builtin_amdgcn_s_setprio(0);

            afc[0] = afn0; afc[1] = afn1;
        }
    }
    __syncthreads();   // all waves done reading xs

    // ---- tanh epilogue -> H-tile into LDS (same buffer), XOR-swizzled ----
    // C/D: col(t)=lane&31, row(f)=(reg&3)+8*(reg>>2)+4*hi5 (+mf*32)
    float4 cbv[2][4];
    #pragma unroll
    for (int a = 0; a < 2; ++a)
        #pragma unroll
        for (int g = 0; g < 4; ++g)
            cbv[a][g] = *(const float4*)(conv_b + fbase + a * 32 + g * 8 + hi5 * 4);
    #pragma unroll
    for (int n = 0; n < 4; ++n) {
        int tl = n * 32 + l31;
        uint32_t hb = (uint32_t)(tl * 512) ^ (uint32_t)(fbase * 2)
                    ^ (uint32_t)(hi5 * 8) ^ (uint32_t)((tl & 7) << 4);
        #pragma unroll
        for (int a = 0; a < 2; ++a) {
            f32x16 d = acc[a][n];
            #pragma unroll
            for (int g = 0; g < 4; ++g) {
                float4 cb = cbv[a][g];
                uint2 pk;
                pk.x = pack_bf2(tanh_fast(d[4*g+0] + cb.x), tanh_fast(d[4*g+1] + cb.y));
                pk.y = pack_bf2(tanh_fast(d[4*g+2] + cb.z), tanh_fast(d[4*g+3] + cb.w));
                *(uint2*)((char*)xs + (hb ^ (uint32_t)(a * 64) ^ (uint32_t)(g * 16))) = pk;
            }
        }
    }
    __syncthreads();

    // ---- P GEMM: wave = 64 s-rows x (32 score cols + 32 t cols), K=256, steps of 16 ----
    const int lb = wid & 1;              // label block (cols lb*32..+31)
    const int rh = wid >> 1;             // row half (s rows rh*64..+63)
    f32x16 ps[2], pt[2];
    #pragma unroll
    for (int m = 0; m < 2; ++m) {
        ps[m] = (f32x16){0,0,0,0,0,0,0,0,0,0,0,0,0,0,0,0};
        pt[m] = (f32x16){0,0,0,0,0,0,0,0,0,0,0,0,0,0,0,0};
    }
    uint32_t pb[2];
    #pragma unroll
    for (int m = 0; m < 2; ++m) {
        int sl = rh * 64 + m * 32 + l31;
        pb[m] = (uint32_t)(sl * 512) ^ (uint32_t)(hi5 * 16) ^ (uint32_t)((sl & 7) << 4);
    }
    const unsigned short* wpb = W2k3 + ((size_t)hi5 * 128 + lb * 32 + l31) * 8;

    #pragma unroll
    for (int kc = 0; kc < 16; ++kc) {
        bf16x8v ha[2], w2s, w2t;
        #pragma unroll
        for (int m = 0; m < 2; ++m)
            ha[m] = *(const bf16x8v*)((const char*)xs + (pb[m] ^ (uint32_t)(kc * 32)));
        w2s = *(const bf16x8v*)(wpb + kc * 2048);
        w2t = *(const bf16x8v*)(wpb + kc * 2048 + 512);
        __builtin_amdgcn_s_setprio(1);
        #pragma unroll
        for (int m = 0; m < 2; ++m) {
            ps[m] = __builtin_amdgcn_mfma_f32_32x32x16_bf16(ha[m], w2s, ps[m], 0, 0, 0);
            pt[m] = __builtin_amdgcn_mfma_f32_32x32x16_bf16(ha[m], w2t, pt[m], 0, 0, 0);
        }
        __builtin_amdgcn_s_setprio(0);
    }

    // ---- Lane-local online-softmax partials over this wave's 64 rows ----
    // lane col = label lb*32 + l31 (score and t in same lane); rows all valid.
    float mx = -1e30f;
    #pragma unroll
    for (int m = 0; m < 2; ++m)
        #pragma unroll
        for (int i = 0; i < 16; ++i)
            mx = fmaxf(mx, ps[m][i]);
    float se = 0.f, st = 0.f;
    #pragma unroll
    for (int m = 0; m < 2; ++m)
        #pragma unroll
        for (int i = 0; i < 16; ++i) {
            float e = __expf(ps[m][i] - mx);
            se += e;
            st += e * pt[m][i];
        }
    {   // combine lane <-> lane+32 (same col, other 32 rows)
        float mo  = __shfl_xor(mx, 32);
        float seo = __shfl_xor(se, 32);
        float sto = __shfl_xor(st, 32);
        float M  = fmaxf(mx, mo);
        float w0 = __expf(mx - M), w1 = __expf(mo - M);
        se = se * w0 + seo * w1;
        st = st * w0 + sto * w1;
        mx = M;
    }
    if (lane < 32) {
        int l = lb * 32 + lane;
        if (l < LDIM) {
            size_t o = ((((size_t)b * NT + tile) * 2 + rh) * LDIM + l) * 3;
            part[o] = mx; part[o + 1] = se; part[o + 2] = st;
        }
    }
}

// ---- Final: exact position t=4096 (fp32, coalesced Wt01) + merge 2*NT chunks ----
__global__ __launch_bounds__(256) void final_kernel(
    const int* __restrict__ ids, const float* __restrict__ emb,
    const float* __restrict__ Wt01, const float* __restrict__ conv_b,
    const float* __restrict__ U_w, const float* __restrict__ final_w,
    const float* __restrict__ part, const float* __restrict__ final_b,
    float* __restrict__ out)
{
    __shared__ float x0[EDIM], x1[EDIM], hsh[FDIM], rsc[256], rtv[256];
    const int b = blockIdx.x, t = threadIdx.x;   // 256 threads

    {
        int id0 = ids[b * SDIM + 4094];
        int id1 = ids[b * SDIM + 4095];
        x0[t] = emb[(size_t)id0 * EDIM + t];
        x1[t] = emb[(size_t)id1 * EDIM + t];
    }
    __syncthreads();

    {
        const float2* wt = (const float2*)Wt01;
        float a0 = 0.f, a1 = 0.f, a2 = 0.f, a3 = 0.f;
        #pragma unroll 4
        for (int e = 0; e < 256; e += 4) {
            float2 w0 = wt[(e + 0) * 256 + t];
            float2 w1 = wt[(e + 1) * 256 + t];
            float2 w2 = wt[(e + 2) * 256 + t];
            float2 w3 = wt[(e + 3) * 256 + t];
            a0 = fmaf(w0.x, x0[e + 0], fmaf(w0.y, x1[e + 0], a0));
            a1 = fmaf(w1.x, x0[e + 1], fmaf(w1.y, x1[e + 1], a1));
            a2 = fmaf(w2.x, x0[e + 2], fmaf(w2.y, x1[e + 2], a2));
            a3 = fmaf(w3.x, x0[e + 3], fmaf(w3.y, x1[e + 3], a3));
        }
        hsh[t] = tanhf(conv_b[t] + ((a0 + a1) + (a2 + a3)));
    }
    __syncthreads();

    {
        const int l = t & 63, c = t >> 6;
        float sc = 0.f, tv = 0.f;
        if (l < LDIM) {
            const float4* uw = (const float4*)(U_w + (size_t)l * FDIM + c * 64);
            const float4* fw = (const float4*)(final_w + (size_t)l * FDIM + c * 64);
            const float4* hh = (const float4*)(hsh + c * 64);
            #pragma unroll
            for (int i = 0; i < 16; ++i) {
                float4 h = hh[i], u = uw[i], w = fw[i];
                sc = fmaf(h.x, u.x, fmaf(h.y, u.y, fmaf(h.z, u.z, fmaf(h.w, u.w, sc))));
                tv = fmaf(h.x, w.x, fmaf(h.y, w.y, fmaf(h.z, w.z, fmaf(h.w, w.w, tv))));
            }
        }
        rsc[t] = sc; rtv[t] = tv;
    }
    __syncthreads();

    if (t < LDIM) {
        float sc = rsc[t] + rsc[t + 64] + rsc[t + 128] + rsc[t + 192];
        float tv = rtv[t] + rtv[t + 64] + rtv[t + 128] + rtv[t + 192];
        float mx = sc, se = 1.0f, st = tv;       // seed with position 4096
        for (int c = 0; c < 2 * NT; ++c) {
            size_t o = (((size_t)b * 2 * NT + c) * LDIM + t) * 3;
            float mo = part[o], seo = part[o + 1], sto = part[o + 2];
            float M  = fmaxf(mx, mo);
            float w0 = __expf(mx - M), w1 = __expf(mo - M);
            se = se * w0 + seo * w1;
            st = st * w0 + sto * w1;
            mx = M;
        }
        out[b * LDIM + t] = st / se + final_b[t];
    }
}

extern "C" void kernel_launch(void* const* d_in, const int* in_sizes, int n_in,
                              void* d_out, int out_size, void* d_ws, size_t ws_size,
                              hipStream_t stream)
{
    const int*   ids     = (const int*)d_in[0];
    const float* emb     = (const float*)d_in[1];
    const float* conv_w  = (const float*)d_in[2];
    const float* conv_b  = (const float*)d_in[3];
    const float* U_w     = (const float*)d_in[4];
    const float* final_w = (const float*)d_in[5];
    const float* final_b = (const float*)d_in[6];

    char* ws = (char*)d_ws;
    size_t offE  = 0;
    size_t szE   = (size_t)30522 * 256 * 2;          // 15,627,264 B
    size_t offWb = offE + szE;
    size_t szWb  = 262144 * 2;                       // 524,288 B
    size_t offW2 = offWb + szWb;
    size_t szW2  = 32768 * 2;                        // 65,536 B
    size_t offWt = offW2 + szW2;
    size_t szWt  = 65536 * 2 * 4;                    // 524,288 B (fp32 taps 0,1)
    size_t offZ  = offWt + szWt;
    size_t szZ   = 512;
    size_t offP  = offZ + szZ;                       // 32*64*50*3 fp32 = 1,228,800 B

    unsigned short* embb = (unsigned short*)(ws + offE);
    unsigned short* Wb3  = (unsigned short*)(ws + offWb);
    unsigned short* W2k3 = (unsigned short*)(ws + offW2);
    float*          Wt01 = (float*)(ws + offWt);
    uint32_t*       zp   = (uint32_t*)(ws + offZ);
    float*          prt  = (float*)(ws + offP);

    prep_all<<<3816, 256, 0, stream>>>(emb, conv_w, U_w, final_w, embb, Wb3, W2k3, Wt01, zp);
    fused_kernel<<<dim3(NT, BDIM), 256, 0, stream>>>(ids, embb, Wb3, conv_b, W2k3, zp, prt);
    final_kernel<<<BDIM, 256, 0, stream>>>(ids, emb, Wt01, conv_b, U_w, final_w,
                                           prt, final_b, (float*)d_out);
}

// Round 14
// 108.388 us; speedup vs baseline: 1.0596x; 1.0596x over previous
//
#include <hip/hip_runtime.h>
#include <hip/hip_bf16.h>
#include <stdint.h>

#define BDIM 32
#define SDIM 4096
#define SP1  4097
#define EDIM 256
#define FDIM 256
#define LDIM 50
#define TTILE 128
#define NT    32   // 32 tiles x 128 = 4096; t=4096 computed by tile-31 blocks (chunk 32)

typedef __attribute__((ext_vector_type(8))) short bf16x8v;
typedef __attribute__((ext_vector_type(4))) float f32x4;

__device__ __forceinline__ unsigned short f2bf(float f) {
    union { float f; uint32_t u; } v; v.f = f;
    uint32_t u = v.u;
    uint32_t r = (u + 0x7fffu + ((u >> 16) & 1u)) >> 16;
    return (unsigned short)r;
}

__device__ __forceinline__ float bf2f(unsigned short s) {
    union { uint32_t u; float f; } v; v.u = (uint32_t)s << 16; return v.f;
}

// tanh(x) = 1 - 2/(1+e^{2x}); v_rcp_f32 (~1ulp) is plenty vs bf16 storage noise.
__device__ __forceinline__ float tanh_fast(float x) {
    float e = __expf(2.0f * x);
    float r = __builtin_amdgcn_rcpf(e + 1.0f);
    return fmaf(-2.0f, r, 1.0f);
}

// Scalar casts -> compiler emits v_cvt_pk_bf16_f32 (m240: don't hand-write).
__device__ __forceinline__ uint32_t pack_bf2(float lo, float hi) {
    union { __hip_bfloat162 v; uint32_t u; } cv;
    cv.v = __halves2bfloat162(__float2bfloat16(lo), __float2bfloat16(hi));
    return cv.u;
}

__device__ __forceinline__ void load_lds16(const void* g, uint32_t* l) {
    __builtin_amdgcn_global_load_lds(
        (const __attribute__((address_space(1))) uint32_t*)g,
        (__attribute__((address_space(3))) uint32_t*)l, 16, 0, 0);
}

// ---- Prep: embb (fp32->bf16 table), Wb2[g][hi4][f][8], W2k, zero page ----
__global__ void prep_all(const float* __restrict__ emb, const float* __restrict__ conv_w,
                         const float* __restrict__ U_w, const float* __restrict__ final_w,
                         unsigned short* __restrict__ embb, unsigned short* __restrict__ Wb2,
                         unsigned short* __restrict__ W2k, uint32_t* __restrict__ zp)
{
    int o = blockIdx.x * 256 + threadIdx.x;          // grid 3816 -> o < 976896
    size_t eo = (size_t)o * 8;
    if (eo < (size_t)30522 * 256) {
        float4 v0 = *(const float4*)(emb + eo);
        float4 v1 = *(const float4*)(emb + eo + 4);
        union { unsigned short u[8]; uint4 q; } pk;
        pk.u[0] = f2bf(v0.x); pk.u[1] = f2bf(v0.y); pk.u[2] = f2bf(v0.z); pk.u[3] = f2bf(v0.w);
        pk.u[4] = f2bf(v1.x); pk.u[5] = f2bf(v1.y); pk.u[6] = f2bf(v1.z); pk.u[7] = f2bf(v1.w);
        *(uint4*)(embb + eo) = pk.q;
    }
    if (o < 262144) {
        int kk = o & 1023, f = o >> 10;
        int e = kk & 255, k = kk >> 8;
        int g = kk >> 5, h4 = (kk >> 3) & 3, j = kk & 7;
        Wb2[((size_t)(g * 4 + h4) * 256 + f) * 8 + j] = f2bf(conv_w[f * 1024 + e * 4 + k]);
    }
    if (o < 32768) {
        int j = o & 7, c = (o >> 3) & 127, g = o >> 10;
        int k = g * 8 + j, l = c & 63;
        float v = 0.f;
        if (l < LDIM) v = (c < 64) ? U_w[l * FDIM + k] : final_w[l * FDIM + k];
        W2k[o] = f2bf(v);
    }
    if (o < 128) zp[o] = 0;
}

// ---- Fused: gather -> conv1d+tanh (LDS H-tile) -> scores|t GEMM -> softmax partials.
//      Tile-31 blocks additionally compute position t=4096 (rows 128/129 stay staged). ----
__global__ __launch_bounds__(256, 2) void fused_kernel(
    const int* __restrict__ ids, const unsigned short* __restrict__ embb,
    const unsigned short* __restrict__ Wb2, const float* __restrict__ conv_b,
    const unsigned short* __restrict__ W2k, const uint32_t* __restrict__ zp,
    const float* __restrict__ U_w, const float* __restrict__ final_w,
    float* __restrict__ part)
{
    __shared__ uint32_t xs[133 * 128];   // 68,096 B: x rows 0..130 + 1KB scratch (rows 131/132)

    const int tid  = threadIdx.x;
    const int lane = tid & 63;
    const int wid  = tid >> 6;
    const int b    = blockIdx.y;
    const int tile = blockIdx.x;
    const int t0   = tile * TTILE;
    const int l15  = lane & 15;
    const int hi4  = lane >> 4;
    const int q    = lane & 31;
    const int half = lane >> 5;

    // ---- stage rows 0..130 (p = t0-2+r): all ids first, then all gathers ----
    {
        int nid[17];
        #pragma unroll
        for (int j = 0; j < 17; ++j) {
            int r0 = wid * 2 + j * 8;
            int r  = r0 + half;
            int p  = t0 - 2 + r;
            nid[j] = -1;
            if (r0 < 131 && r < 131 && (unsigned)p < SDIM)
                nid[j] = ids[b * SDIM + p];
        }
        const unsigned short* zs = (const unsigned short*)zp + q * 8;
        #pragma unroll
        for (int j = 0; j < 17; ++j) {
            int r0 = wid * 2 + j * 8;
            if (r0 >= 131) continue;                 // wave-uniform guard
            int r = r0 + half;
            const unsigned short* s = (nid[j] >= 0)
                ? embb + (size_t)nid[j] * EDIM + (((uint32_t)(q * 16) ^ ((uint32_t)(r & 7) << 4)) >> 1)
                : zs;
            load_lds16(s, &xs[r0 * 128]);
        }
    }
    __syncthreads();

    // ---- Conv GEMM: wave = 64 filters (M) x 128 positions (N), K=1024 ----
    // Weights streamed from Wb2 [g][hi4][f][8]: per-lane base + g*16KB + a*256B.
    const int fbase = wid * 64;
    const unsigned short* afbase = Wb2 + (size_t)(hi4 * 256 + fbase + l15) * 8;

    f32x4 acc[4][8];
    #pragma unroll
    for (int a = 0; a < 4; ++a)
        #pragma unroll
        for (int n = 0; n < 8; ++n) acc[a][n] = (f32x4){0.f, 0.f, 0.f, 0.f};

    bf16x8v afc[4];
    #pragma unroll
    for (int a = 0; a < 4; ++a) afc[a] = *(const bf16x8v*)(afbase + a * 128);   // g=0

    #pragma unroll 1
    for (int k = 0; k < 4; ++k) {
        uint32_t bb[8];
        #pragma unroll
        for (int n = 0; n < 8; ++n) {
            int r = n * 16 + l15 + k;
            bb[n] = (uint32_t)(r * 512) ^ (uint32_t)(hi4 * 16) ^ (uint32_t)((r & 7) << 4);
        }
        const unsigned short* afg = afbase + (size_t)k * 65536;
        #pragma unroll
        for (int es = 0; es < 8; ++es) {
            // prefetch next g's A-fragments (always 4 loads in flight)
            const unsigned short* nxt = (es < 7)
                ? (afg + (size_t)(es + 1) * 8192)
                : (afbase + (size_t)((k + 1) & 3) * 65536);
            bf16x8v afn[4];
            #pragma unroll
            for (int a = 0; a < 4; ++a) afn[a] = *(const bf16x8v*)(nxt + a * 128);

            bf16x8v bfr[8];
            #pragma unroll
            for (int n = 0; n < 8; ++n)
                bfr[n] = *(const bf16x8v*)((const char*)xs + (bb[n] ^ (uint32_t)(es * 64)));

            __builtin_amdgcn_s_setprio(1);
            #pragma unroll
            for (int a = 0; a < 4; ++a)
                #pragma unroll
                for (int n = 0; n < 8; ++n)
                    acc[a][n] = __builtin_amdgcn_mfma_f32_16x16x32_bf16(afc[a], bfr[n], acc[a][n], 0, 0, 0);
            __builtin_amdgcn_s_setprio(0);

            #pragma unroll
            for (int a = 0; a < 4; ++a) afc[a] = afn[a];
        }
    }
    __syncthreads();   // all waves done reading xs

    // ---- tanh epilogue -> H-tile rows 0..127 in same buffer, XOR-swizzled ----
    float4 cb[4];
    #pragma unroll
    for (int a = 0; a < 4; ++a)
        cb[a] = *(const float4*)(conv_b + fbase + a * 16 + hi4 * 4);
    #pragma unroll
    for (int n = 0; n < 8; ++n) {
        int tl = n * 16 + l15;
        uint32_t hb = (uint32_t)(tl * 512) ^ (uint32_t)(hi4 * 8)
                    ^ (uint32_t)(fbase * 2) ^ (uint32_t)((tl & 7) << 4);
        #pragma unroll
        for (int a = 0; a < 4; ++a) {
            f32x4 d = acc[a][n];
            uint2 pk;
            pk.x = pack_bf2(tanh_fast(d[0] + cb[a].x), tanh_fast(d[1] + cb[a].y));
            pk.y = pack_bf2(tanh_fast(d[2] + cb[a].z), tanh_fast(d[3] + cb[a].w));
            *(uint2*)((char*)xs + (hb ^ (uint32_t)(a * 32))) = pk;
        }
    }
    __syncthreads();

    // ---- P GEMM: 128 s-rows x 32 cols per wave (cbase..+15 scores, +64 t), K=256 ----
    const int cbase = wid * 16;
    f32x4 p2[8][2];
    #pragma unroll
    for (int m = 0; m < 8; ++m) { p2[m][0] = (f32x4){0,0,0,0}; p2[m][1] = (f32x4){0,0,0,0}; }

    uint32_t pb[8];
    #pragma unroll
    for (int m = 0; m < 8; ++m) {
        int sl = m * 16 + l15;
        pb[m] = (uint32_t)(sl * 512) ^ (uint32_t)(hi4 * 16) ^ (uint32_t)((sl & 7) << 4);
    }
    const unsigned short* wp0 = W2k + (size_t)(hi4 * 128 + cbase + l15) * 8;

    #pragma unroll
    for (int step = 0; step < 8; ++step) {
        bf16x8v ha[8], w2[2];
        #pragma unroll
        for (int m = 0; m < 8; ++m)
            ha[m] = *(const bf16x8v*)((const char*)xs + (pb[m] ^ (uint32_t)(step * 64)));
        w2[0] = *(const bf16x8v*)(wp0 + step * 4096);
        w2[1] = *(const bf16x8v*)(wp0 + 512 + step * 4096);
        __builtin_amdgcn_s_setprio(1);
        #pragma unroll
        for (int m = 0; m < 8; ++m) {
            p2[m][0] = __builtin_amdgcn_mfma_f32_16x16x32_bf16(ha[m], w2[0], p2[m][0], 0, 0, 0);
            p2[m][1] = __builtin_amdgcn_mfma_f32_16x16x32_bf16(ha[m], w2[1], p2[m][1], 0, 0, 0);
        }
        __builtin_amdgcn_s_setprio(0);
    }

    // ---- Lane-local online-softmax partials (all 128 rows valid: t0+127 <= 4095) ----
    float mx = -1e30f;
    #pragma unroll
    for (int m = 0; m < 8; ++m)
        #pragma unroll
        for (int i = 0; i < 4; ++i)
            mx = fmaxf(mx, p2[m][0][i]);
    float se = 0.f, st = 0.f;
    #pragma unroll
    for (int m = 0; m < 8; ++m)
        #pragma unroll
        for (int i = 0; i < 4; ++i) {
            float e = __expf(p2[m][0][i] - mx);
            se += e;
            st += e * p2[m][1][i];
        }
    #pragma unroll
    for (int d = 16; d <= 32; d <<= 1) {
        float mo  = __shfl_xor(mx, d);
        float seo = __shfl_xor(se, d);
        float sto = __shfl_xor(st, d);
        float M  = fmaxf(mx, mo);
        float w0 = __expf(mx - M), w1 = __expf(mo - M);
        se = se * w0 + seo * w1;
        st = st * w0 + sto * w1;
        mx = M;
    }
    if (lane < 16) {
        int l = cbase + l15;
        if (l < LDIM) {
            size_t o = (((size_t)b * (NT + 1) + tile) * LDIM + l) * 3;
            part[o] = mx; part[o + 1] = se; part[o + 2] = st;
        }
    }

    // ---- tile-31 extra: position t=4096 (taps 0,1 from staged rows 128,129) ----
    if (tile == NT - 1) {
        __syncthreads();                 // all P-GEMM/softmax done; xs rows 0..127 reusable
        float* hs4 = (float*)xs;         // [256] H(4096)
        float* rsc = hs4 + 256;          // [256]
        float* rtv = hs4 + 512;          // [256]
        const int f = tid;

        float a0 = 0.f, a1 = 0.f;
        #pragma unroll 2
        for (int tap = 0; tap < 2; ++tap) {
            int r = 128 + tap;
            uint32_t swz = (uint32_t)((r & 7) << 4);
            #pragma unroll
            for (int es = 0; es < 8; ++es) {
                #pragma unroll
                for (int h4 = 0; h4 < 4; ++h4) {
                    int g = tap * 8 + es;
                    bf16x8v w = *(const bf16x8v*)(Wb2 + ((size_t)(g * 4 + h4) * 256 + f) * 8);
                    int e0 = es * 32 + h4 * 8;
                    uint32_t byte = (uint32_t)(r * 512) + ((uint32_t)(e0 * 2) ^ swz);
                    const unsigned short* xv = (const unsigned short*)((const char*)xs + byte);
                    float s = 0.f;
                    #pragma unroll
                    for (int j = 0; j < 8; ++j)
                        s = fmaf(bf2f((unsigned short)w[j]), bf2f(xv[j]), s);
                    if (tap == 0) a0 += s; else a1 += s;
                }
            }
        }
        // note: row 128/129 may be beyond staged range only if p>=SDIM (never: p=4094,4095)
        float hv = tanh_fast(conv_b[f] + a0 + a1);
        __syncthreads();                 // everyone done reading xs (H-tile) from P-phase scratch
        hs4[f] = hv;
        __syncthreads();

        {
            const int l = tid & 63, c = tid >> 6;    // c: f-chunk [c*64, c*64+64)
            float sc = 0.f, tv = 0.f;
            if (l < LDIM) {
                const float4* uw = (const float4*)(U_w + (size_t)l * FDIM + c * 64);
                const float4* fw = (const float4*)(final_w + (size_t)l * FDIM + c * 64);
                const float4* hh = (const float4*)(hs4 + c * 64);
                #pragma unroll
                for (int i = 0; i < 16; ++i) {
                    float4 h = hh[i], u = uw[i], w = fw[i];
                    sc = fmaf(h.x, u.x, fmaf(h.y, u.y, fmaf(h.z, u.z, fmaf(h.w, u.w, sc))));
                    tv = fmaf(h.x, w.x, fmaf(h.y, w.y, fmaf(h.z, w.z, fmaf(h.w, w.w, tv))));
                }
            }
            rsc[tid] = sc; rtv[tid] = tv;
        }
        __syncthreads();

        if (tid < LDIM) {
            float sc = rsc[tid] + rsc[tid + 64] + rsc[tid + 128] + rsc[tid + 192];
            float tv = rtv[tid] + rtv[tid + 64] + rtv[tid + 128] + rtv[tid + 192];
            size_t o = (((size_t)b * (NT + 1) + NT) * LDIM + tid) * 3;
            part[o] = sc; part[o + 1] = 1.0f; part[o + 2] = tv;
        }
    }
}

// ---- Final: merge 33 partial chunks -> logits ----
__global__ __launch_bounds__(64) void final_kernel(
    const float* __restrict__ part, const float* __restrict__ final_b,
    float* __restrict__ out)
{
    int b = blockIdx.x, l = threadIdx.x;
    if (l >= LDIM) return;
    float mx = -1e30f, se = 0.f, st = 0.f;
    for (int c = 0; c <= NT; ++c) {
        size_t o = (((size_t)b * (NT + 1) + c) * LDIM + l) * 3;
        float mo = part[o], seo = part[o + 1], sto = part[o + 2];
        float M  = fmaxf(mx, mo);
        float w0 = __expf(mx - M), w1 = __expf(mo - M);
        se = se * w0 + seo * w1;
        st = st * w0 + sto * w1;
        mx = M;
    }
    out[b * LDIM + l] = st / se + final_b[l];
}

extern "C" void kernel_launch(void* const* d_in, const int* in_sizes, int n_in,
                              void* d_out, int out_size, void* d_ws, size_t ws_size,
                              hipStream_t stream)
{
    const int*   ids     = (const int*)d_in[0];
    const float* emb     = (const float*)d_in[1];
    const float* conv_w  = (const float*)d_in[2];
    const float* conv_b  = (const float*)d_in[3];
    const float* U_w     = (const float*)d_in[4];
    const float* final_w = (const float*)d_in[5];
    const float* final_b = (const float*)d_in[6];

    char* ws = (char*)d_ws;
    size_t offE  = 0;
    size_t szE   = (size_t)30522 * 256 * 2;          // 15,627,264 B
    size_t offWb = offE + szE;
    size_t szWb  = 256 * 1024 * 2;                   // 524,288 B
    size_t offW2 = offWb + szWb;
    size_t szW2  = 32768 * 2;                        // 65,536 B
    size_t offZ  = offW2 + szW2;
    size_t szZ   = 512;
    size_t offP  = offZ + szZ;                       // 32*33*50*3 fp32 = 633,600 B

    unsigned short* embb = (unsigned short*)(ws + offE);
    unsigned short* Wb2  = (unsigned short*)(ws + offWb);
    unsigned short* W2k  = (unsigned short*)(ws + offW2);
    uint32_t*       zp   = (uint32_t*)(ws + offZ);
    float*          prt  = (float*)(ws + offP);

    prep_all<<<3816, 256, 0, stream>>>(emb, conv_w, U_w, final_w, embb, Wb2, W2k, zp);
    fused_kernel<<<dim3(NT, BDIM), 256, 0, stream>>>(ids, embb, Wb2, conv_b, W2k, zp,
                                                     U_w, final_w, prt);
    final_kernel<<<BDIM, 64, 0, stream>>>(prt, final_b, (float*)d_out);
}

// Round 15
// 92.752 us; speedup vs baseline: 1.2383x; 1.1686x over previous
//
#include <hip/hip_runtime.h>
#include <hip/hip_bf16.h>
#include <stdint.h>

#define BDIM 32
#define SDIM 4096
#define SP1  4097
#define EDIM 256
#define FDIM 256
#define LDIM 50
#define TTILE 128
#define NT    32   // 32 tiles x 128 = 4096; t=4096 = special blocks (chunk 32)

typedef __attribute__((ext_vector_type(8))) short bf16x8v;
typedef __attribute__((ext_vector_type(4))) float f32x4;

__device__ __forceinline__ unsigned short f2bf(float f) {
    union { float f; uint32_t u; } v; v.f = f;
    uint32_t u = v.u;
    uint32_t r = (u + 0x7fffu + ((u >> 16) & 1u)) >> 16;
    return (unsigned short)r;
}

// tanh(x) = 1 - 2/(1+e^{2x}); v_rcp_f32 (~1ulp) is plenty vs bf16 storage noise.
__device__ __forceinline__ float tanh_fast(float x) {
    float e = __expf(2.0f * x);
    float r = __builtin_amdgcn_rcpf(e + 1.0f);
    return fmaf(-2.0f, r, 1.0f);
}

// Scalar casts -> compiler emits v_cvt_pk_bf16_f32 (m240: don't hand-write).
__device__ __forceinline__ uint32_t pack_bf2(float lo, float hi) {
    union { __hip_bfloat162 v; uint32_t u; } cv;
    cv.v = __halves2bfloat162(__float2bfloat16(lo), __float2bfloat16(hi));
    return cv.u;
}

__device__ __forceinline__ void load_lds16(const void* g, uint32_t* l) {
    __builtin_amdgcn_global_load_lds(
        (const __attribute__((address_space(1))) uint32_t*)g,
        (__attribute__((address_space(3))) uint32_t*)l, 16, 0, 0);
}

// ---- Prep: embb (fp32->bf16 table), Wb2[g][hi4][f][8], W2k, Wt01[e][f] fp32, zero page ----
__global__ void prep_all(const float* __restrict__ emb, const float* __restrict__ conv_w,
                         const float* __restrict__ U_w, const float* __restrict__ final_w,
                         unsigned short* __restrict__ embb, unsigned short* __restrict__ Wb2,
                         unsigned short* __restrict__ W2k, float* __restrict__ Wt01,
                         uint32_t* __restrict__ zp)
{
    int o = blockIdx.x * 256 + threadIdx.x;          // grid 3816 -> o < 976896
    size_t eo = (size_t)o * 8;
    if (eo < (size_t)30522 * 256) {
        float4 v0 = *(const float4*)(emb + eo);
        float4 v1 = *(const float4*)(emb + eo + 4);
        union { unsigned short u[8]; uint4 q; } pk;
        pk.u[0] = f2bf(v0.x); pk.u[1] = f2bf(v0.y); pk.u[2] = f2bf(v0.z); pk.u[3] = f2bf(v0.w);
        pk.u[4] = f2bf(v1.x); pk.u[5] = f2bf(v1.y); pk.u[6] = f2bf(v1.z); pk.u[7] = f2bf(v1.w);
        *(uint4*)(embb + eo) = pk.q;
    }
    if (o < 262144) {
        int kk = o & 1023, f = o >> 10;
        int e = kk & 255, k = kk >> 8;
        int g = kk >> 5, h4 = (kk >> 3) & 3, j = kk & 7;
        Wb2[((size_t)(g * 4 + h4) * 256 + f) * 8 + j] = f2bf(conv_w[f * 1024 + e * 4 + k]);
    }
    if (o < 32768) {
        int j = o & 7, c = (o >> 3) & 127, g = o >> 10;
        int k = g * 8 + j, l = c & 63;
        float v = 0.f;
        if (l < LDIM) v = (c < 64) ? U_w[l * FDIM + k] : final_w[l * FDIM + k];
        W2k[o] = f2bf(v);
    }
    if (o < 65536) {
        int f = o & 255, e = o >> 8;                 // Wt01[e][f] = taps 0,1 (fp32 exact)
        Wt01[(size_t)o * 2]     = conv_w[f * 1024 + e * 4];
        Wt01[(size_t)o * 2 + 1] = conv_w[f * 1024 + e * 4 + 1];
    }
    if (o < 128) zp[o] = 0;
}

// ---- Fused: gather -> conv1d+tanh (LDS H-tile) -> scores|t GEMM -> softmax partials.
//      tile==NT special blocks: exact fp32 t=4096 -> 33rd partial chunk (disjoint branch,
//      keeps main-path VGPR at 112 — R14's in-path fold cost 16 VGPR and a block/CU). ----
__global__ __launch_bounds__(256, 2) void fused_kernel(
    const int* __restrict__ ids, const unsigned short* __restrict__ embb,
    const unsigned short* __restrict__ Wb2, const float* __restrict__ conv_b,
    const unsigned short* __restrict__ W2k, const uint32_t* __restrict__ zp,
    const float* __restrict__ Wt01, const float* __restrict__ emb,
    const float* __restrict__ U_w, const float* __restrict__ final_w,
    float* __restrict__ part)
{
    __shared__ uint32_t xs[132 * 128];   // 67,584 B: x rows 0..130, reused as H-tile

    const int tid  = threadIdx.x;
    const int lane = tid & 63;
    const int wid  = tid >> 6;
    const int b    = blockIdx.y;
    const int tile = blockIdx.x;

    if (tile < NT) {
        const int t0   = tile * TTILE;
        const int l15  = lane & 15;
        const int hi4  = lane >> 4;
        const int q    = lane & 31;
        const int half = lane >> 5;

        // ---- stage rows 0..130 (p = t0-2+r): all ids first, then all gathers ----
        {
            int nid[17];
            #pragma unroll
            for (int j = 0; j < 17; ++j) {
                int r0 = wid * 2 + j * 8;
                int r  = r0 + half;
                int p  = t0 - 2 + r;
                nid[j] = -1;
                if (r0 < 131 && r < 131 && (unsigned)p < SDIM)
                    nid[j] = ids[b * SDIM + p];
            }
            const unsigned short* zs = (const unsigned short*)zp + q * 8;
            #pragma unroll
            for (int j = 0; j < 17; ++j) {
                int r0 = wid * 2 + j * 8;
                if (r0 >= 131) continue;             // wave-uniform guard
                int r = r0 + half;
                const unsigned short* s = (nid[j] >= 0)
                    ? embb + (size_t)nid[j] * EDIM + (((uint32_t)(q * 16) ^ ((uint32_t)(r & 7) << 4)) >> 1)
                    : zs;
                load_lds16(s, &xs[r0 * 128]);
            }
        }
        __syncthreads();

        // ---- Conv GEMM: wave = 64 filters (M) x 128 positions (N), K=1024 ----
        const int fbase = wid * 64;
        const unsigned short* afbase = Wb2 + (size_t)(hi4 * 256 + fbase + l15) * 8;

        f32x4 acc[4][8];
        #pragma unroll
        for (int a = 0; a < 4; ++a)
            #pragma unroll
            for (int n = 0; n < 8; ++n) acc[a][n] = (f32x4){0.f, 0.f, 0.f, 0.f};

        bf16x8v afc[4];
        #pragma unroll
        for (int a = 0; a < 4; ++a) afc[a] = *(const bf16x8v*)(afbase + a * 128);   // g=0

        #pragma unroll 1
        for (int k = 0; k < 4; ++k) {
            uint32_t bb[8];
            #pragma unroll
            for (int n = 0; n < 8; ++n) {
                int r = n * 16 + l15 + k;
                bb[n] = (uint32_t)(r * 512) ^ (uint32_t)(hi4 * 16) ^ (uint32_t)((r & 7) << 4);
            }
            const unsigned short* afg = afbase + (size_t)k * 65536;
            #pragma unroll
            for (int es = 0; es < 8; ++es) {
                // prefetch next g's A-fragments (always 4 loads in flight)
                const unsigned short* nxt = (es < 7)
                    ? (afg + (size_t)(es + 1) * 8192)
                    : (afbase + (size_t)((k + 1) & 3) * 65536);
                bf16x8v afn[4];
                #pragma unroll
                for (int a = 0; a < 4; ++a) afn[a] = *(const bf16x8v*)(nxt + a * 128);

                bf16x8v bfr[8];
                #pragma unroll
                for (int n = 0; n < 8; ++n)
                    bfr[n] = *(const bf16x8v*)((const char*)xs + (bb[n] ^ (uint32_t)(es * 64)));

                __builtin_amdgcn_s_setprio(1);
                #pragma unroll
                for (int a = 0; a < 4; ++a)
                    #pragma unroll
                    for (int n = 0; n < 8; ++n)
                        acc[a][n] = __builtin_amdgcn_mfma_f32_16x16x32_bf16(afc[a], bfr[n], acc[a][n], 0, 0, 0);
                __builtin_amdgcn_s_setprio(0);

                #pragma unroll
                for (int a = 0; a < 4; ++a) afc[a] = afn[a];
            }
        }
        __syncthreads();   // all waves done reading xs

        // ---- tanh epilogue -> H-tile into LDS (same buffer), XOR-swizzled ----
        float4 cb[4];
        #pragma unroll
        for (int a = 0; a < 4; ++a)
            cb[a] = *(const float4*)(conv_b + fbase + a * 16 + hi4 * 4);
        #pragma unroll
        for (int n = 0; n < 8; ++n) {
            int tl = n * 16 + l15;
            uint32_t hb = (uint32_t)(tl * 512) ^ (uint32_t)(hi4 * 8)
                        ^ (uint32_t)(fbase * 2) ^ (uint32_t)((tl & 7) << 4);
            #pragma unroll
            for (int a = 0; a < 4; ++a) {
                f32x4 d = acc[a][n];
                uint2 pk;
                pk.x = pack_bf2(tanh_fast(d[0] + cb[a].x), tanh_fast(d[1] + cb[a].y));
                pk.y = pack_bf2(tanh_fast(d[2] + cb[a].z), tanh_fast(d[3] + cb[a].w));
                *(uint2*)((char*)xs + (hb ^ (uint32_t)(a * 32))) = pk;
            }
        }
        __syncthreads();

        // ---- P GEMM: 128 s-rows x 32 cols per wave (cbase..+15 scores, +64 t), K=256 ----
        const int cbase = wid * 16;
        f32x4 p2[8][2];
        #pragma unroll
        for (int m = 0; m < 8; ++m) { p2[m][0] = (f32x4){0,0,0,0}; p2[m][1] = (f32x4){0,0,0,0}; }

        uint32_t pb[8];
        #pragma unroll
        for (int m = 0; m < 8; ++m) {
            int sl = m * 16 + l15;
            pb[m] = (uint32_t)(sl * 512) ^ (uint32_t)(hi4 * 16) ^ (uint32_t)((sl & 7) << 4);
        }
        const unsigned short* wp0 = W2k + (size_t)(hi4 * 128 + cbase + l15) * 8;

        #pragma unroll
        for (int step = 0; step < 8; ++step) {
            bf16x8v ha[8], w2[2];
            #pragma unroll
            for (int m = 0; m < 8; ++m)
                ha[m] = *(const bf16x8v*)((const char*)xs + (pb[m] ^ (uint32_t)(step * 64)));
            w2[0] = *(const bf16x8v*)(wp0 + step * 4096);
            w2[1] = *(const bf16x8v*)(wp0 + 512 + step * 4096);
            __builtin_amdgcn_s_setprio(1);
            #pragma unroll
            for (int m = 0; m < 8; ++m) {
                p2[m][0] = __builtin_amdgcn_mfma_f32_16x16x32_bf16(ha[m], w2[0], p2[m][0], 0, 0, 0);
                p2[m][1] = __builtin_amdgcn_mfma_f32_16x16x32_bf16(ha[m], w2[1], p2[m][1], 0, 0, 0);
            }
            __builtin_amdgcn_s_setprio(0);
        }

        // ---- Lane-local online-softmax partials (all 128 rows valid) ----
        float mx = -1e30f;
        #pragma unroll
        for (int m = 0; m < 8; ++m)
            #pragma unroll
            for (int i = 0; i < 4; ++i)
                mx = fmaxf(mx, p2[m][0][i]);
        float se = 0.f, st = 0.f;
        #pragma unroll
        for (int m = 0; m < 8; ++m)
            #pragma unroll
            for (int i = 0; i < 4; ++i) {
                float e = __expf(p2[m][0][i] - mx);
                se += e;
                st += e * p2[m][1][i];
            }
        #pragma unroll
        for (int d = 16; d <= 32; d <<= 1) {
            float mo  = __shfl_xor(mx, d);
            float seo = __shfl_xor(se, d);
            float sto = __shfl_xor(st, d);
            float M  = fmaxf(mx, mo);
            float w0 = __expf(mx - M), w1 = __expf(mo - M);
            se = se * w0 + seo * w1;
            st = st * w0 + sto * w1;
            mx = M;
        }
        if (lane < 16) {
            int l = cbase + l15;
            if (l < LDIM) {
                size_t o = (((size_t)b * (NT + 1) + tile) * LDIM + l) * 3;
                part[o] = mx; part[o + 1] = se; part[o + 2] = st;
            }
        }
    } else {
        // ---- special block: exact position t=4096 (fp32) -> 33rd partial chunk ----
        float* fs  = (float*)xs;
        float* x0  = fs;
        float* x1  = fs + 256;
        float* hsh = fs + 512;
        float* rsc = fs + 768;
        float* rtv = fs + 1024;
        const int t = tid;

        {
            int id0 = ids[b * SDIM + 4094];
            int id1 = ids[b * SDIM + 4095];
            x0[t] = emb[(size_t)id0 * EDIM + t];
            x1[t] = emb[(size_t)id1 * EDIM + t];
        }
        __syncthreads();

        {
            const float2* wt = (const float2*)Wt01;
            float a0 = 0.f, a1 = 0.f, a2 = 0.f, a3 = 0.f;
            #pragma unroll 4
            for (int e = 0; e < 256; e += 4) {
                float2 w0 = wt[(e + 0) * 256 + t];
                float2 w1 = wt[(e + 1) * 256 + t];
                float2 w2 = wt[(e + 2) * 256 + t];
                float2 w3 = wt[(e + 3) * 256 + t];
                a0 = fmaf(w0.x, x0[e + 0], fmaf(w0.y, x1[e + 0], a0));
                a1 = fmaf(w1.x, x0[e + 1], fmaf(w1.y, x1[e + 1], a1));
                a2 = fmaf(w2.x, x0[e + 2], fmaf(w2.y, x1[e + 2], a2));
                a3 = fmaf(w3.x, x0[e + 3], fmaf(w3.y, x1[e + 3], a3));
            }
            hsh[t] = tanhf(conv_b[t] + ((a0 + a1) + (a2 + a3)));
        }
        __syncthreads();

        {
            const int l = t & 63, c = t >> 6;
            float sc = 0.f, tv = 0.f;
            if (l < LDIM) {
                const float4* uw = (const float4*)(U_w + (size_t)l * FDIM + c * 64);
                const float4* fw = (const float4*)(final_w + (size_t)l * FDIM + c * 64);
                const float4* hh = (const float4*)(hsh + c * 64);
                #pragma unroll
                for (int i = 0; i < 16; ++i) {
                    float4 h = hh[i], u = uw[i], w = fw[i];
                    sc = fmaf(h.x, u.x, fmaf(h.y, u.y, fmaf(h.z, u.z, fmaf(h.w, u.w, sc))));
                    tv = fmaf(h.x, w.x, fmaf(h.y, w.y, fmaf(h.z, w.z, fmaf(h.w, w.w, tv))));
                }
            }
            rsc[t] = sc; rtv[t] = tv;
        }
        __syncthreads();

        if (t < LDIM) {
            float sc = rsc[t] + rsc[t + 64] + rsc[t + 128] + rsc[t + 192];
            float tv = rtv[t] + rtv[t + 64] + rtv[t + 128] + rtv[t + 192];
            size_t o = (((size_t)b * (NT + 1) + NT) * LDIM + t) * 3;
            part[o] = sc; part[o + 1] = 1.0f; part[o + 2] = tv;
        }
    }
}

// ---- Final: merge 33 partial chunks -> logits ----
__global__ __launch_bounds__(64) void final_kernel(
    const float* __restrict__ part, const float* __restrict__ final_b,
    float* __restrict__ out)
{
    int b = blockIdx.x, l = threadIdx.x;
    if (l >= LDIM) return;
    float mx = -1e30f, se = 0.f, st = 0.f;
    for (int c = 0; c <= NT; ++c) {
        size_t o = (((size_t)b * (NT + 1) + c) * LDIM + l) * 3;
        float mo = part[o], seo = part[o + 1], sto = part[o + 2];
        float M  = fmaxf(mx, mo);
        float w0 = __expf(mx - M), w1 = __expf(mo - M);
        se = se * w0 + seo * w1;
        st = st * w0 + sto * w1;
        mx = M;
    }
    out[b * LDIM + l] = st / se + final_b[l];
}

extern "C" void kernel_launch(void* const* d_in, const int* in_sizes, int n_in,
                              void* d_out, int out_size, void* d_ws, size_t ws_size,
                              hipStream_t stream)
{
    const int*   ids     = (const int*)d_in[0];
    const float* emb     = (const float*)d_in[1];
    const float* conv_w  = (const float*)d_in[2];
    const float* conv_b  = (const float*)d_in[3];
    const float* U_w     = (const float*)d_in[4];
    const float* final_w = (const float*)d_in[5];
    const float* final_b = (const float*)d_in[6];

    char* ws = (char*)d_ws;
    size_t offE  = 0;
    size_t szE   = (size_t)30522 * 256 * 2;          // 15,627,264 B
    size_t offWb = offE + szE;
    size_t szWb  = 256 * 1024 * 2;                   // 524,288 B
    size_t offW2 = offWb + szWb;
    size_t szW2  = 32768 * 2;                        // 65,536 B
    size_t offWt = offW2 + szW2;
    size_t szWt  = 65536 * 2 * 4;                    // 524,288 B (fp32 taps 0,1)
    size_t offZ  = offWt + szWt;
    size_t szZ   = 512;
    size_t offP  = offZ + szZ;                       // 32*33*50*3 fp32 = 633,600 B

    unsigned short* embb = (unsigned short*)(ws + offE);
    unsigned short* Wb2  = (unsigned short*)(ws + offWb);
    unsigned short* W2k  = (unsigned short*)(ws + offW2);
    float*          Wt01 = (float*)(ws + offWt);
    uint32_t*       zp   = (uint32_t*)(ws + offZ);
    float*          prt  = (float*)(ws + offP);

    prep_all<<<3816, 256, 0, stream>>>(emb, conv_w, U_w, final_w, embb, Wb2, W2k, Wt01, zp);
    fused_kernel<<<dim3(NT + 1, BDIM), 256, 0, stream>>>(
        ids, embb, Wb2, conv_b, W2k, zp, Wt01, emb, U_w, final_w, prt);
    final_kernel<<<BDIM, 64, 0, stream>>>(prt, final_b, (float*)d_out);
}